// Round 6
// baseline (109.388 us; speedup 1.0000x reference)
//
#include <hip/hip_runtime.h>
#include <math.h>

// MultiWindowAttention B=4,L=2048,H=8,E=D=64 fp32; w = 32<<(h&3).
// Round 12: prep pass -> half-precision K/V in workspace, L2-resident slices.
//   R8-R11 (schedule fixes) all neutral at ~28us: kernel is HBM-bound on
//   band-overlap RE-READS. fp32 slices make the per-XCD working set 8MB
//   (> 4MB L2) so overlap re-reads miss; effective BW 3.7 TB/s.
//   Fix: kernel A converts K -> bf16 in the exact frag-linear LDS image and
//   V -> f16 transposed ([d][j]) into d_ws. Kernel B (main) then streams
//   8KB+8KB per tile as pure dwordx4 copies (no packing VALU), K/V slice
//   drops to 512KB -> per-XCD working set 2MB << L2 -> re-reads hit L2,
//   HBM sees Q + K/V-once + O = ~50MB. Numerics bit-identical (same
//   pack2/packh2, same accumulation order). Fallback to R11 path if ws
//   is too small. Main structure otherwise = R11 (128-row i-tiles, 8
//   waves, band-skip fused QK->exp->PV, 2-deep prefetch, no-drain
//   barriers, XCD pinning, heavy/light pairing).

#define LL 2048
#define HH 8
#define EE 64
#define DD 64
#define RS (HH * EE)   // 512 floats between consecutive seq positions

typedef __attribute__((ext_vector_type(8))) short short8;
typedef __attribute__((ext_vector_type(4))) float floatx4;
typedef __attribute__((ext_vector_type(4))) _Float16 half4;
typedef __attribute__((ext_vector_type(2))) __fp16 fp16x2;   // cvt_pkrtz return type

static __device__ __forceinline__ unsigned f2bf(float f) {
    union { float f; unsigned u; } v; v.f = f;
    return (v.u + 0x7fff + ((v.u >> 16) & 1)) >> 16;   // RNE
}
static __device__ __forceinline__ unsigned pack2(float a, float b) {
    return f2bf(a) | (f2bf(b) << 16);
}
static __device__ __forceinline__ unsigned packh2(float a, float b) {
    union { fp16x2 h; unsigned u; } v;
    v.h = __builtin_amdgcn_cvt_pkrtz(a, b);
    return v.u;
}

// No-drain barrier: LDS writes visible, global loads stay in flight.
static __device__ __forceinline__ void barrier_nodrain() {
    asm volatile("s_waitcnt lgkmcnt(0)" ::: "memory");
    __builtin_amdgcn_s_barrier();
}

// LDS layout (shorts): K bufs [0, 8192) = 2 x 4096; V^T bufs [8192, 17408) = 2 x 4608 (ld=72)
#define K_BUF(cu)  (sAll + (cu) * 4096)
#define V_BUF(cu)  (sAll + 8192 + (cu) * 4608)

// ---- per-t4 fused compute: S^T += K.Q^T, mask, exp, P.V -> acc ----
static __device__ __forceinline__ void compute_tile(
    int j0, const short* __restrict__ kbase, const short* __restrict__ vbase,
    int w, int qb, int iq, int quad, int l15,
    short8 qf0, short8 qf1, floatx4* __restrict__ acc, float& lsum)
{
#pragma unroll
    for (int t4 = 0; t4 < 4; ++t4) {
        const int jb = j0 + t4 * 16;
        if (jb > qb + 15 + w || jb + 15 < qb - w) continue;   // wave-uniform skip
        const bool needMask = ((jb + 15 - qb) > w) || ((qb + 15 - jb) > w);

        const short* kp = kbase + 1024 * t4 + 128 * quad + 8 * l15;
        short8 k0 = *(const short8*)kp;
        short8 k1 = *(const short8*)(kp + 512);
        floatx4 st = {};
        st = __builtin_amdgcn_mfma_f32_16x16x32_bf16(k0, qf0, st, 0, 0, 0);
        st = __builtin_amdgcn_mfma_f32_16x16x32_bf16(k1, qf1, st, 0, 0, 0);

        float pr[4];
        const int jq = jb + quad * 4;
#pragma unroll
        for (int r = 0; r < 4; ++r) {
            float x = st[r];
            if (needMask) {
                const int di = iq - (jq + r);
                x = (di <= w && di >= -w) ? x : -INFINITY;
            }
            pr[r] = __expf(x);
            lsum += pr[r];
        }
        half4 pf;
        {
            union { half4 v; unsigned u[2]; } pu;
            pu.u[0] = packh2(pr[0], pr[1]);
            pu.u[1] = packh2(pr[2], pr[3]);
            pf = pu.v;
        }
#pragma unroll
        for (int nt = 0; nt < 4; ++nt) {
            half4 vf = *(const half4*)(vbase + (nt * 16 + l15) * 72 + t4 * 16 + quad * 4);
            acc[nt] = __builtin_amdgcn_mfma_f32_16x16x16f16(pf, vf, acc[nt], 0, 0, 0);
        }
    }
}

// ============================ PREP KERNEL ============================
// One block per (b,h,jt) 64-row tile. Writes:
//   wsK[tile][4096 shorts] : K tile bf16, frag-linear (exact LDS image)
//   wsV[tile][4096 shorts] : V^T tile f16, [d][j] packed (ld=64)
__global__ __launch_bounds__(256, 8) void mwa_prep(
    const float* __restrict__ K, const float* __restrict__ V,
    short* __restrict__ wsK, short* __restrict__ wsV)
{
    const int t   = blockIdx.x;
    const int jt  = t & 31;
    const int h   = (t >> 5) & 7;
    const int b   = t >> 8;
    const int j0  = jt << 6;
    const int tid = threadIdx.x;

    const float* Kt = K + ((size_t)(b * LL + j0) * HH + h) * EE;
    const float* Vt = V + ((size_t)(b * LL + j0) * HH + h) * DD;
    short* wk = wsK + (size_t)((b * HH + h) * 32 + jt) * 4096;
    short* wv = wsV + (size_t)((b * HH + h) * 32 + jt) * 4096;

    __shared__ float sV[64 * 68];

    // K: frag-linear bf16 (2 units of 8 floats per thread)
#pragma unroll
    for (int uu = 0; uu < 2; ++uu) {
        const int u = tid + uu * 256;
        const int row = u >> 3, cg = u & 7;
        const float4* src = (const float4*)(Kt + (size_t)row * RS + cg * 8);
        float4 f0 = src[0], f1 = src[1];
        uint4 o = { pack2(f0.x,f0.y), pack2(f0.z,f0.w),
                    pack2(f1.x,f1.y), pack2(f1.z,f1.w) };
        *(uint4*)&wk[((((row >> 4) * 2 + (cg >> 2)) * 4 + (cg & 3)) * 16 + (row & 15)) * 8] = o;
    }

    // V: fp32 tile -> LDS (padded), then transposed f16 pairs -> ws
    {
        const int row = tid >> 2, dg = (tid & 3) << 4;
        const float4* src = (const float4*)(Vt + (size_t)row * RS + dg);
        float4 f0 = src[0], f1 = src[1], f2 = src[2], f3 = src[3];
        *(float4*)&sV[row * 68 + dg     ] = f0;
        *(float4*)&sV[row * 68 + dg + 4 ] = f1;
        *(float4*)&sV[row * 68 + dg + 8 ] = f2;
        *(float4*)&sV[row * 68 + dg + 12] = f3;
    }
    __syncthreads();
    {
        const int d = tid >> 2, jp = (tid & 3) << 4;
        unsigned o[8];
#pragma unroll
        for (int r = 0; r < 8; ++r)
            o[r] = packh2(sV[(jp + 2 * r) * 68 + d], sV[(jp + 2 * r + 1) * 68 + d]);
        *(uint4*)&wv[d * 64 + jp    ] = *(uint4*)&o[0];
        *(uint4*)&wv[d * 64 + jp + 8] = *(uint4*)&o[4];
    }
}

// ============================ MAIN KERNEL ============================
__global__ __launch_bounds__(512, 4) void mwa_r12(
    const float* __restrict__ Q,
    const short* __restrict__ wsK,
    const short* __restrict__ wsV,
    float* __restrict__ O)
{
    const int tid  = threadIdx.x;
    const int lane = tid & 63;
    const int wv   = tid >> 6;          // 0..7, wave owns q-rows wv*16..+15
    const int quad = lane >> 4;
    const int l15  = lane & 15;

    // ---- task decode (= R9-R11): heavy classes in gid<256; gid&7 fixed per (b,h) ----
    const int gid   = blockIdx.x;
    const int heavy = (gid >> 8) == 0;
    const int c     = gid & 255;
    const int it    = c >> 4;           // 0..15 (128-row i-tiles)
    const int rem   = c & 15;
    const int b     = rem >> 2;
    const int z     = rem & 3;
    const int hb    = z >> 1;
    const int p     = z & 1;
    const int h     = hb * 4 + (heavy ? (3 - p) : p);
    const int i0    = it << 7;
    const int w     = 32 << (h & 3);

    alignas(16) __shared__ short sAll[17408];   // 34816 B

    const float* Qb  = Q + ((size_t)b * LL * HH + h) * EE;
    const short* wKt = wsK + (size_t)((b * HH + h) * 32) * 4096;
    const short* wVt = wsV + (size_t)((b * HH + h) * 32) * 4096;
    float*       Ob  = O + ((size_t)b * LL * HH + h) * DD;

    // ---- stage Q (128 rows, bf16, ld=72, pre-scaled by 1/8); grab frags ----
    {
        const float sc = 0.125f;    // 2^-3: exact in bf16, folds softmax scale
        const int row = tid >> 2, cc = (tid & 3) << 4;
        const float4* src = (const float4*)(Qb + (size_t)(i0 + row) * RS + cc);
        float4 f0 = src[0], f1 = src[1], f2 = src[2], f3 = src[3];
        uint4 u0 = { pack2(sc*f0.x,sc*f0.y), pack2(sc*f0.z,sc*f0.w),
                     pack2(sc*f1.x,sc*f1.y), pack2(sc*f1.z,sc*f1.w) };
        uint4 u1 = { pack2(sc*f2.x,sc*f2.y), pack2(sc*f2.z,sc*f2.w),
                     pack2(sc*f3.x,sc*f3.y), pack2(sc*f3.z,sc*f3.w) };
        uint4* dst = (uint4*)&sAll[row * 72 + cc];   // 18432 B scratch
        dst[0] = u0; dst[1] = u1;
    }
    __syncthreads();
    short8 qf0, qf1;
    {
        const short* qp = &sAll[(wv * 16 + l15) * 72 + quad * 8];
        qf0 = *(const short8*)qp;
        qf1 = *(const short8*)(qp + 32);
    }
    __syncthreads();   // Q-frag reads done before K/V staging overwrites

    const int jt_lo = max(0, i0 - w) >> 6;
    const int jt_hi = min(LL - 1, i0 + 127 + w) >> 6;
    const int n     = jt_hi - jt_lo + 1;    // 3..10

    const int vOff = (tid >> 3) * 72 + (tid & 7) * 8;   // V^T LDS dst (ld=72)

    // issue: 2 dwordx4 from ws (contiguous 8KB images)
#define ISSUE(jti_, kr_, vr_)                                        \
    {                                                                \
        kr_ = *(const uint4*)&wKt[(size_t)(jti_) * 4096 + tid * 8];  \
        vr_ = *(const uint4*)&wVt[(size_t)(jti_) * 4096 + tid * 8];  \
    }
    // stage: pure 16B copies (compiler inserts counted vmcnt waits)
#define STAGE(bufIdx, kr_, vr_)                                      \
    {                                                                \
        *(uint4*)&K_BUF(bufIdx)[tid * 8] = kr_;                      \
        *(uint4*)&V_BUF(bufIdx)[vOff]    = vr_;                      \
    }

    // ---- prologue: tile 0 -> buf0; issue tile 1 into set A ----
    uint4 kA, vA, kB, vB;
    ISSUE(jt_lo, kA, vA);
    STAGE(0, kA, vA);
    if (n > 1) ISSUE(jt_lo + 1, kA, vA);
    __syncthreads();   // full drain once at pipeline start: harmless

    floatx4 acc[4] = {};
    float lsum = 0.f;
    const int iq = i0 + wv * 16 + l15;   // this lane's query row (q = l15 in S^T)
    const int qb = i0 + wv * 16;         // wave's q-block base

    for (int s = 0; s < n; s += 2) {
        const int jt = jt_lo + s;
        // ---- even tile s: A holds s+1 -> stage buf1; issue s+2 -> B; compute buf0 ----
        if (s + 2 < n) ISSUE(jt + 2, kB, vB);
        if (s + 1 < n) STAGE(1, kA, vA);
        compute_tile(jt << 6, K_BUF(0), V_BUF(0), w, qb, iq, quad, l15, qf0, qf1, acc, lsum);
        barrier_nodrain();

        if (s + 1 < n) {
            // ---- odd tile s+1: B holds s+2 -> stage buf0; issue s+3 -> A; compute buf1 ----
            if (s + 3 < n) ISSUE(jt + 3, kA, vA);
            if (s + 2 < n) STAGE(0, kB, vB);
            compute_tile((jt + 1) << 6, K_BUF(1), V_BUF(1), w, qb, iq, quad, l15, qf0, qf1, acc, lsum);
            barrier_nodrain();
        }
    }
#undef ISSUE
#undef STAGE

    // ---- epilogue: finish l, normalize, store (per-wave, no merge) ----
    lsum += __shfl_xor(lsum, 16, 64);
    lsum += __shfl_xor(lsum, 32, 64);      // lane (q = l15): row-sum over all j
    float rinv[4];
#pragma unroll
    for (int r = 0; r < 4; ++r) {
        const float lr = __shfl(lsum, quad * 4 + r, 64);
        rinv[r] = 1.0f / lr;
    }
#pragma unroll
    for (int nt = 0; nt < 4; ++nt) {
#pragma unroll
        for (int r = 0; r < 4; ++r) {
            Ob[(size_t)(i0 + wv * 16 + quad * 4 + r) * RS + nt * 16 + l15]
                = acc[nt][r] * rinv[r];
        }
    }
}

// ==================== FALLBACK (R11, fp32 staging) ====================
#define ISSUE_F(jn, kf0_, kf1_, vv_)                                            \
    {                                                                           \
        const float4* src_ = (const float4*)(Kb + (size_t)((jn) + rowp) * RS + cp); \
        kf0_ = src_[0]; kf1_ = src_[1];                                         \
        _Pragma("unroll")                                                       \
        for (int rr_ = 0; rr_ < 8; ++rr_)                                       \
            vv_[rr_] = Vb[(size_t)((jn) + wv * 8 + rr_) * RS + lane];           \
    }
#define STAGE_F(bufIdx, kf0_, kf1_, vv_)                                        \
    {                                                                           \
        uint4 u0_ = { pack2(kf0_.x,kf0_.y), pack2(kf0_.z,kf0_.w),               \
                      pack2(kf1_.x,kf1_.y), pack2(kf1_.z,kf1_.w) };             \
        *(uint4*)&K_BUF(bufIdx)[kWoff] = u0_;                                   \
        uint4 w0_ = { packh2(vv_[0],vv_[1]), packh2(vv_[2],vv_[3]),             \
                      packh2(vv_[4],vv_[5]), packh2(vv_[6],vv_[7]) };           \
        *(uint4*)&V_BUF(bufIdx)[vWoff] = w0_;                                   \
    }

__global__ __launch_bounds__(512, 4) void mwa_r11f(
    const float* __restrict__ Q,
    const float* __restrict__ K,
    const float* __restrict__ V,
    float* __restrict__ O)
{
    const int tid  = threadIdx.x;
    const int lane = tid & 63;
    const int wv   = tid >> 6;
    const int quad = lane >> 4;
    const int l15  = lane & 15;

    const int gid   = blockIdx.x;
    const int heavy = (gid >> 8) == 0;
    const int c     = gid & 255;
    const int it    = c >> 4;
    const int rem   = c & 15;
    const int b     = rem >> 2;
    const int z     = rem & 3;
    const int hb    = z >> 1;
    const int p     = z & 1;
    const int h     = hb * 4 + (heavy ? (3 - p) : p);
    const int i0    = it << 7;
    const int w     = 32 << (h & 3);

    alignas(16) __shared__ short sAll[17408];

    const float* Qb = Q + ((size_t)b * LL * HH + h) * EE;
    const float* Kb = K + ((size_t)b * LL * HH + h) * EE;
    const float* Vb = V + ((size_t)b * LL * HH + h) * DD;
    float*       Ob = O + ((size_t)b * LL * HH + h) * DD;

    {
        const float sc = 0.125f;
        const int row = tid >> 2, cc = (tid & 3) << 4;
        const float4* src = (const float4*)(Qb + (size_t)(i0 + row) * RS + cc);
        float4 f0 = src[0], f1 = src[1], f2 = src[2], f3 = src[3];
        uint4 u0 = { pack2(sc*f0.x,sc*f0.y), pack2(sc*f0.z,sc*f0.w),
                     pack2(sc*f1.x,sc*f1.y), pack2(sc*f1.z,sc*f1.w) };
        uint4 u1 = { pack2(sc*f2.x,sc*f2.y), pack2(sc*f2.z,sc*f2.w),
                     pack2(sc*f3.x,sc*f3.y), pack2(sc*f3.z,sc*f3.w) };
        uint4* dst = (uint4*)&sAll[row * 72 + cc];
        dst[0] = u0; dst[1] = u1;
    }
    __syncthreads();
    short8 qf0, qf1;
    {
        const short* qp = &sAll[(wv * 16 + l15) * 72 + quad * 8];
        qf0 = *(const short8*)qp;
        qf1 = *(const short8*)(qp + 32);
    }
    __syncthreads();

    const int jt_lo = max(0, i0 - w) >> 6;
    const int jt_hi = min(LL - 1, i0 + 127 + w) >> 6;
    const int n     = jt_hi - jt_lo + 1;

    const int rowp  = tid >> 3, cp = (tid & 7) << 3;
    const int jtw   = rowp >> 4, l15w = rowp & 15, ks = cp >> 5, q0w = (cp >> 3) & 3;
    const int kWoff = (((jtw * 2 + ks) * 4 + q0w) * 16 + l15w) * 8;
    const int vWoff = lane * 72 + wv * 8;

    float4 kA0, kA1; float vA[8];
    float4 kB0, kB1; float vB[8];
    ISSUE_F(jt_lo << 6, kA0, kA1, vA);
    STAGE_F(0, kA0, kA1, vA);
    if (n > 1) ISSUE_F((jt_lo + 1) << 6, kA0, kA1, vA);
    __syncthreads();

    floatx4 acc[4] = {};
    float lsum = 0.f;
    const int iq = i0 + wv * 16 + l15;
    const int qb = i0 + wv * 16;

    for (int s = 0; s < n; s += 2) {
        const int jt = jt_lo + s;
        if (s + 2 < n) ISSUE_F((jt + 2) << 6, kB0, kB1, vB);
        if (s + 1 < n) STAGE_F(1, kA0, kA1, vA);
        compute_tile(jt << 6, K_BUF(0), V_BUF(0), w, qb, iq, quad, l15, qf0, qf1, acc, lsum);
        barrier_nodrain();

        if (s + 1 < n) {
            if (s + 3 < n) ISSUE_F((jt + 3) << 6, kA0, kA1, vA);
            if (s + 2 < n) STAGE_F(0, kB0, kB1, vB);
            compute_tile((jt + 1) << 6, K_BUF(1), V_BUF(1), w, qb, iq, quad, l15, qf0, qf1, acc, lsum);
            barrier_nodrain();
        }
    }

    lsum += __shfl_xor(lsum, 16, 64);
    lsum += __shfl_xor(lsum, 32, 64);
    float rinv[4];
#pragma unroll
    for (int r = 0; r < 4; ++r) {
        const float lr = __shfl(lsum, quad * 4 + r, 64);
        rinv[r] = 1.0f / lr;
    }
#pragma unroll
    for (int nt = 0; nt < 4; ++nt) {
#pragma unroll
        for (int r = 0; r < 4; ++r) {
            Ob[(size_t)(i0 + wv * 16 + quad * 4 + r) * RS + nt * 16 + l15]
                = acc[nt][r] * rinv[r];
        }
    }
}

extern "C" void kernel_launch(void* const* d_in, const int* in_sizes, int n_in,
                              void* d_out, int out_size, void* d_ws, size_t ws_size,
                              hipStream_t stream)
{
    const float* Q = (const float*)d_in[0];
    const float* K = (const float*)d_in[1];
    const float* V = (const float*)d_in[2];
    float* O = (float*)d_out;

    const size_t wsNeed = (size_t)2 * 4 * 8 * 32 * 4096 * sizeof(short);  // 16 MiB
    if (ws_size >= wsNeed) {
        short* wsK = (short*)d_ws;
        short* wsV = wsK + (size_t)4 * 8 * 32 * 4096;
        hipLaunchKernelGGL(mwa_prep, dim3(1024), dim3(256), 0, stream, K, V, wsK, wsV);
        hipLaunchKernelGGL(mwa_r12, dim3(512), dim3(512), 0, stream, Q, wsK, wsV, O);
    } else {
        hipLaunchKernelGGL(mwa_r11f, dim3(512), dim3(512), 0, stream, Q, K, V, O);
    }
}